// Round 1
// baseline (355.214 us; speedup 1.0000x reference)
//
#include <hip/hip_runtime.h>

// TPlanesEnc: B=4, N=131072, P=512, F=32
// coords: [B*N, 3] f32 in [-1,1]; tplanes: [3, P, P, F] f32; out: [B*N, 3*F] f32
//
// Mapping: 8 lanes per (point, plane); lane handles one float4 of the F=32
// features. Texel rows are 128B contiguous -> 8-lane float4 reads are fully
// coalesced. Output per point is 96 contiguous f32 -> coalesced float4 stores.

#define PS 512
#define FDIM 32

__global__ __launch_bounds__(256) void tplanes_enc_kernel(
    const float* __restrict__ coords,   // [M, 3]
    const float* __restrict__ tplanes,  // [3, PS, PS, FDIM]
    float* __restrict__ out,            // [M, 3*FDIM]
    int M)
{
    int tid = blockIdx.x * blockDim.x + threadIdx.x;
    int total = M * 3 * (FDIM / 4);     // one thread per float4 chunk
    if (tid >= total) return;

    int chunk = tid & 7;                // FDIM/4 = 8 chunks
    int pp    = tid >> 3;               // (point, plane) pair
    int plane = pp % 3;
    int point = pp / 3;

    // [-1,1] -> [0,1]
    float cx = coords[point * 3 + 0] * 0.5f + 0.5f;
    float cy = coords[point * 3 + 1] * 0.5f + 0.5f;
    float cz = coords[point * 3 + 2] * 0.5f + 0.5f;

    // plane 0: (x,y); plane 1: (x,z); plane 2: (z,y)
    float u = (plane == 2) ? cz : cx;
    float v = (plane == 1) ? cz : cy;

    float x = fminf(fmaxf(u * (float)PS - 0.5f, 0.0f), (float)(PS - 1));
    float y = fminf(fmaxf(v * (float)PS - 0.5f, 0.0f), (float)(PS - 1));
    float x0f = floorf(x);
    float y0f = floorf(y);
    int xi0 = (int)x0f;
    int yi0 = (int)y0f;
    int xi1 = min(xi0 + 1, PS - 1);
    int yi1 = min(yi0 + 1, PS - 1);
    float fx = x - x0f;
    float fy = y - y0f;

    const float4* base = (const float4*)(tplanes + (size_t)plane * PS * PS * FDIM);
    // float4 index of texel row (y, x): ((y*PS + x)*FDIM)/4 = (y*PS + x)*8
    int o00 = (yi0 * PS + xi0) * 8 + chunk;
    int o01 = (yi0 * PS + xi1) * 8 + chunk;
    int o10 = (yi1 * PS + xi0) * 8 + chunk;
    int o11 = (yi1 * PS + xi1) * 8 + chunk;

    float4 f00 = base[o00];
    float4 f01 = base[o01];
    float4 f10 = base[o10];
    float4 f11 = base[o11];

    // match reference: (f00*(1-fx)+f01*fx)*(1-fy) + (f10*(1-fx)+f11*fx)*fy
    float gx = 1.0f - fx;
    float gy = 1.0f - fy;
    float4 r;
    r.x = (f00.x * gx + f01.x * fx) * gy + (f10.x * gx + f11.x * fx) * fy;
    r.y = (f00.y * gx + f01.y * fx) * gy + (f10.y * gx + f11.y * fx) * fy;
    r.z = (f00.z * gx + f01.z * fx) * gy + (f10.z * gx + f11.z * fx) * fy;
    r.w = (f00.w * gx + f01.w * fx) * gy + (f10.w * gx + f11.w * fx) * fy;

    // out[point][plane*FDIM + chunk*4 .. +3] -> float4 index pp*8 + chunk
    ((float4*)out)[(size_t)pp * 8 + chunk] = r;
}

extern "C" void kernel_launch(void* const* d_in, const int* in_sizes, int n_in,
                              void* d_out, int out_size, void* d_ws, size_t ws_size,
                              hipStream_t stream) {
    const float* coords  = (const float*)d_in[0];
    const float* tplanes = (const float*)d_in[1];
    float* out = (float*)d_out;

    int M = in_sizes[0] / 3;            // B*N points
    int total = M * 3 * (FDIM / 4);
    int block = 256;
    int grid = (total + block - 1) / block;
    tplanes_enc_kernel<<<grid, block, 0, stream>>>(coords, tplanes, out, M);
}